// Round 1
// baseline (91.586 us; speedup 1.0000x reference)
//
#include <hip/hip_runtime.h>
#include <math.h>

// Problem constants (fixed by the reference): N=50000, 8 types, dim_q=64, neurons=64.
#define NUM_TYPES 8
#define DIM 64          // dim_q == num_neurons == 64
#define SEG 8192        // per-type segment capacity (n_t ~ 6250, huge margin)
#define BM 128          // atoms per tile
#define QS_STRIDE 132   // 128 + 4: keeps float4 alignment, breaks write conflicts

// ---------------------------------------------------------------------------
// Kernel 1: bucket atoms by type into 8 fixed segments of the workspace.
// Per-block LDS histogram -> 8 global atomicAdds per block (low contention).
// Also initializes out[0] = N * b1 (harness poisons d_out with 0xAA).
// ---------------------------------------------------------------------------
__global__ __launch_bounds__(256) void scatter_kernel(
    const int* __restrict__ Z, int* __restrict__ fill, int* __restrict__ sorted,
    const float* __restrict__ b1, float* __restrict__ out, int N)
{
    __shared__ int cnt[NUM_TYPES];
    __shared__ int base[NUM_TYPES];
    int tid = threadIdx.x;
    if (tid < NUM_TYPES) cnt[tid] = 0;
    __syncthreads();

    int i = blockIdx.x * 256 + tid;
    int z = 0, r = 0;
    bool valid = (i < N);
    if (valid) {
        z = Z[i];
        r = atomicAdd(&cnt[z], 1);   // LDS atomic, cheap
    }
    __syncthreads();
    if (tid < NUM_TYPES) base[tid] = atomicAdd(&fill[tid], cnt[tid]);
    __syncthreads();
    if (valid) {
        int p = base[z] + r;
        if (p < SEG) sorted[z * SEG + p] = i;  // overflow guard (cannot trigger at N=50000/8)
    }
    if (i == 0) out[0] = (float)N * b1[0];
}

// ---------------------------------------------------------------------------
// Kernel 2: per-tile GEMM-style MLP. Tile = 128 atoms (one type) x 64 neurons.
// Thread tile: 8 atoms x 4 neurons (32 fp32 accumulators), block = 256 threads.
// LDS: Qs[d][a] transposed (33 KB), Ws[d][k] (16 KB) -> ~50 KB, fits static 64 KB.
// ---------------------------------------------------------------------------
__global__ __launch_bounds__(256) void mlp_kernel(
    const float* __restrict__ desc, const float* __restrict__ W0,
    const float* __restrict__ b0, const float* __restrict__ W1,
    const int* __restrict__ sorted, float* __restrict__ out)
{
    __shared__ float Qs[DIM][QS_STRIDE];   // Qs[d][atom]
    __shared__ float Ws[DIM][DIM];         // Ws[d][k]  (same layout as W0[t])
    __shared__ int   slots[BM];
    __shared__ float b0s[DIM];
    __shared__ float W1s[DIM];
    __shared__ float wsum[4];

    const int t    = blockIdx.x >> 6;        // type  (grid = 8 * 64)
    const int tile = blockIdx.x & 63;        // tile within segment
    const int tid  = threadIdx.x;

    if (tid < BM) slots[tid] = sorted[t * SEG + tile * BM + tid];
    __syncthreads();
    if (slots[0] < 0) return;                // fully-empty tile (uniform exit)

    // --- stage W0[t] (4096 floats), b0[t], W1[t] ---
    {
        const float4* w0v = (const float4*)(W0 + t * DIM * DIM);
        float4* wsv = (float4*)&Ws[0][0];
        #pragma unroll
        for (int i = 0; i < 4; ++i) wsv[tid + i * 256] = w0v[tid + i * 256];
        if (tid < DIM) { b0s[tid] = b0[t * DIM + tid]; W1s[tid] = W1[t * DIM + tid]; }
    }

    // --- stage Q tile, transposed: 128 rows x 16 float4 = 2048 float4 ---
    #pragma unroll
    for (int it = 0; it < 8; ++it) {
        int f  = tid + it * 256;
        int a  = f >> 4;             // atom row (16 consecutive threads per row: coalesced)
        int dv = (f & 15) << 2;      // starting d of the float4
        int idx = slots[a];
        float4 q = (idx >= 0) ? *(const float4*)(desc + (size_t)idx * DIM + dv)
                              : make_float4(0.f, 0.f, 0.f, 0.f);
        Qs[dv + 0][a] = q.x; Qs[dv + 1][a] = q.y;
        Qs[dv + 2][a] = q.z; Qs[dv + 3][a] = q.w;
    }
    __syncthreads();

    // --- compute: thread (ag,kg) owns atoms ag*8..+7, neurons kg*4..+3 ---
    const int ag = tid & 15;
    const int kg = tid >> 4;
    const int a0 = ag * 8;
    const int k0 = kg * 4;

    float acc[8][4] = {};
    #pragma unroll 4
    for (int d = 0; d < DIM; ++d) {
        float4 qa = *(const float4*)&Qs[d][a0];
        float4 qb = *(const float4*)&Qs[d][a0 + 4];
        float4 w  = *(const float4*)&Ws[d][k0];
        float q[8] = {qa.x, qa.y, qa.z, qa.w, qb.x, qb.y, qb.z, qb.w};
        #pragma unroll
        for (int i = 0; i < 8; ++i) {
            acc[i][0] += q[i] * w.x;
            acc[i][1] += q[i] * w.y;
            acc[i][2] += q[i] * w.z;
            acc[i][3] += q[i] * w.w;
        }
    }

    // --- epilogue: tanh, dot with W1, mask padded atoms, reduce ---
    float bk[4], wk[4];
    #pragma unroll
    for (int j = 0; j < 4; ++j) { bk[j] = b0s[k0 + j]; wk[j] = W1s[k0 + j]; }

    float e = 0.f;
    #pragma unroll
    for (int i = 0; i < 8; ++i) {
        if (slots[a0 + i] >= 0) {
            float s = 0.f;
            #pragma unroll
            for (int j = 0; j < 4; ++j)
                s += tanhf(acc[i][j] + bk[j]) * wk[j];
            e += s;
        }
    }

    // wave reduce (64 lanes), then cross-wave via LDS, one atomicAdd per block
    #pragma unroll
    for (int o = 32; o > 0; o >>= 1) e += __shfl_down(e, o, 64);
    if ((tid & 63) == 0) wsum[tid >> 6] = e;
    __syncthreads();
    if (tid == 0) atomicAdd(out, wsum[0] + wsum[1] + wsum[2] + wsum[3]);
}

// ---------------------------------------------------------------------------
extern "C" void kernel_launch(void* const* d_in, const int* in_sizes, int n_in,
                              void* d_out, int out_size, void* d_ws, size_t ws_size,
                              hipStream_t stream)
{
    const float* desc = (const float*)d_in[0];
    const float* W0   = (const float*)d_in[1];
    const float* b0   = (const float*)d_in[2];
    const float* W1   = (const float*)d_in[3];
    const float* b1   = (const float*)d_in[4];
    const int*   Z    = (const int*)d_in[5];
    const int N = in_sizes[5];

    // workspace: fill[8] at offset 0, sorted[8*8192] at offset 64 (~256.1 KB total)
    int* fill   = (int*)d_ws;
    int* sorted = (int*)((char*)d_ws + 64);

    hipMemsetAsync(fill, 0, NUM_TYPES * sizeof(int), stream);
    hipMemsetAsync(sorted, 0xFF, NUM_TYPES * SEG * sizeof(int), stream);  // -1

    scatter_kernel<<<(N + 255) / 256, 256, 0, stream>>>(
        Z, fill, sorted, b1, (float*)d_out, N);

    mlp_kernel<<<NUM_TYPES * (SEG / BM), 256, 0, stream>>>(
        desc, W0, b0, W1, sorted, (float*)d_out);
}